// Round 1
// baseline (111.254 us; speedup 1.0000x reference)
//
#include <hip/hip_runtime.h>

typedef unsigned short u16;
typedef __bf16 bf16x8 __attribute__((ext_vector_type(8)));
typedef float f32x4 __attribute__((ext_vector_type(4)));
typedef u16 u16x8 __attribute__((ext_vector_type(8)));

// kT[t][c][r]: bf16 bits of conv kernel, transposed so B-fragment k-reads are contiguous.
__device__ __align__(16) u16 g_kT[27 * 64 * 64];

__device__ __forceinline__ u16 f2bf(float f) {
    unsigned int u = __float_as_uint(f);
    u += 0x7FFFu + ((u >> 16) & 1u);   // RNE
    return (u16)(u >> 16);
}

// ---------------------------------------------------------------------------
// Build kT[27][64][64] from w1..w4 (+ fold self-connection into center tap).
// k rows r: r<16 -> scalar input i=r ; r>=16 -> i=(r-16)/3, m=(r-16)%3
// k cols c: c<16 -> scalar output o=c ; c>=16 -> o=(c-16)/3, n=(c-16)%3
// ---------------------------------------------------------------------------
__global__ __launch_bounds__(64) void build_k(
    const float* __restrict__ Wsc0, const float* __restrict__ Wsc1,
    const float* __restrict__ w1, const float* __restrict__ w2,
    const float* __restrict__ w3, const float* __restrict__ w4)
{
    const int t = blockIdx.x;      // tap 0..26
    const int c = threadIdx.x;     // output column 0..63
    const int dx = t / 9 - 1, dy = (t / 3) % 3 - 1, dz = t % 3 - 1;
    const float d = sqrtf((float)(dx * dx + dy * dy + dz * dz));
    const float step = 1.5f / 9.0f;
    float emb[8];
#pragma unroll
    for (int k = 0; k < 8; ++k) {
        float diff = (d - (float)(k + 1) * step) / step;
        float q = diff * diff;
        emb[k] = (q < 1.0f) ? 1.14136f * expf(2.0f - 2.0f / (1.0f - q)) : 0.0f;
    }
    const float dn = fmaxf(d, 1e-12f);
    const float s3 = 1.7320508075688772f;
    const float sh1[3] = { s3 * (float)dx / dn, s3 * (float)dy / dn, s3 * (float)dz / dn };
    const float alpha  = 0.17677669529663687f;          // 1/sqrt(2*MUL)
    const float alpha3 = alpha * 0.57735026918962576f;  // alpha/sqrt(3)

    u16* outp = &g_kT[(t * 64 + c) * 64];
    if (c < 16) {
        const int o = c;
#pragma unroll
        for (int i = 0; i < 16; ++i) {
            float W1 = 0.f, W4 = 0.f;
#pragma unroll
            for (int k = 0; k < 8; ++k) {
                W1 += emb[k] * w1[k * 256 + i * 16 + o];
                W4 += emb[k] * w4[k * 256 + i * 16 + o];
            }
            W1 *= (1.0f / 27.0f); W4 *= (1.0f / 27.0f);
            float v0 = alpha * W1;
            if (t == 13) v0 += 0.25f * Wsc0[i * 16 + o];   // sc scalar block
            outp[i] = f2bf(v0);
            const float base = alpha3 * W4;
#pragma unroll
            for (int m = 0; m < 3; ++m) outp[16 + 3 * i + m] = f2bf(base * sh1[m]);
        }
    } else {
        const int o = (c - 16) / 3, nc = (c - 16) % 3;
#pragma unroll
        for (int i = 0; i < 16; ++i) {
            float W2 = 0.f, W3 = 0.f;
#pragma unroll
            for (int k = 0; k < 8; ++k) {
                W2 += emb[k] * w2[k * 256 + i * 16 + o];
                W3 += emb[k] * w3[k * 256 + i * 16 + o];
            }
            W2 *= (1.0f / 27.0f); W3 *= (1.0f / 27.0f);
            outp[i] = f2bf(alpha * W2 * sh1[nc]);
#pragma unroll
            for (int m = 0; m < 3; ++m) {
                float v = (m == nc) ? alpha * W3 : 0.0f;
                if (t == 13 && m == nc) v += 0.25f * Wsc1[i * 16 + o];  // sc vector block
                outp[16 + 3 * i + m] = f2bf(v);
            }
        }
    }
}

// ---------------------------------------------------------------------------
// Implicit-GEMM conv: block = (b, X, y0..y0+1) -> M=64 positions, N=64 ch.
// LDS tile: [dx(3)][yi(4)][zid(34)][ch(64)] bf16, z-stride padded to 72.
// ---------------------------------------------------------------------------
#define ZS 72
#define LDS_ELEMS (12 * 34 * ZS)

__global__ __launch_bounds__(256) void conv_mfma(
    const float* __restrict__ x, float* __restrict__ out)
{
    __shared__ __align__(16) u16 xt[LDS_ELEMS];
    const int bid = blockIdx.x;
    const int b   = bid >> 9;
    const int X   = (bid >> 4) & 31;
    const int y0  = (bid & 15) << 1;
    const int tid = threadIdx.x;

    // ---- stage: global fp32 -> LDS bf16 (3x4 rows x 34 z x 64 ch) ----
    {
        const int pr = tid >> 2;    // (rid,zid) pair slot 0..63
        const int q  = tid & 3;     // channel quad (16 ch each)
#pragma unroll
        for (int pass = 0; pass < 7; ++pass) {
            const int idx = pass * 64 + pr;
            if (idx < 408) {
                const int rid = idx / 34;
                const int zid = idx - rid * 34;
                const int xin = X + (rid >> 2) - 1;
                const int yin = y0 + (rid & 3) - 1;
                const int zin = zid - 1;
                u16x8 t0 = (u16x8)0, t1 = (u16x8)0;
                if ((unsigned)xin < 32u && (unsigned)yin < 32u && (unsigned)zin < 32u) {
                    const float4* src = reinterpret_cast<const float4*>(
                        x + ((((b * 32 + xin) * 32 + yin) * 32 + zin) * 64 + q * 16));
                    float4 v0 = src[0], v1 = src[1], v2 = src[2], v3 = src[3];
                    t0[0] = f2bf(v0.x); t0[1] = f2bf(v0.y); t0[2] = f2bf(v0.z); t0[3] = f2bf(v0.w);
                    t0[4] = f2bf(v1.x); t0[5] = f2bf(v1.y); t0[6] = f2bf(v1.z); t0[7] = f2bf(v1.w);
                    t1[0] = f2bf(v2.x); t1[1] = f2bf(v2.y); t1[2] = f2bf(v2.z); t1[3] = f2bf(v2.w);
                    t1[4] = f2bf(v3.x); t1[5] = f2bf(v3.y); t1[6] = f2bf(v3.z); t1[7] = f2bf(v3.w);
                }
                u16* dst = &xt[(rid * 34 + zid) * ZS + q * 16];
                *reinterpret_cast<u16x8*>(dst)     = t0;
                *reinterpret_cast<u16x8*>(dst + 8) = t1;
            }
        }
    }
    __syncthreads();

    const int w    = tid >> 6;      // wave 0..3
    const int lane = tid & 63;
    const int l15  = lane & 15;
    const int kg   = lane >> 4;     // k-group 0..3
    const int mh   = w >> 1;        // M half (also y' index)
    const int nh   = w & 1;         // N half
    const int chb  = kg * 8;

    const f32x4 z4 = {0.f, 0.f, 0.f, 0.f};
    f32x4 acc[2][2] = {{z4, z4}, {z4, z4}};

    // 19 non-zero taps (center + 6 faces + 12 edges; 8 corners are exactly 0)
    constexpr int NT = 19;
    constexpr int TAPS[NT] = {1,3,4,5,7,9,10,11,12,13,14,15,16,17,19,21,22,23,25};

#pragma unroll
    for (int ti = 0; ti < NT; ++ti) {
        const int t   = TAPS[ti];
        const int dxt = t / 9, dyt = (t / 3) % 3, dzt = t % 3;   // each in 0..2 (= d+1)
        const int rid = dxt * 4 + mh + dyt;
#pragma unroll
        for (int kb = 0; kb < 2; ++kb) {
            bf16x8 bfr[2], afr[2];
#pragma unroll
            for (int nt = 0; nt < 2; ++nt) {
                const int col = nh * 32 + nt * 16 + l15;
                bfr[nt] = *reinterpret_cast<const bf16x8*>(
                    &g_kT[(t * 64 + col) * 64 + kb * 32 + chb]);
            }
#pragma unroll
            for (int mt = 0; mt < 2; ++mt) {
                const int zid = mt * 16 + l15 + dzt;
                afr[mt] = *reinterpret_cast<const bf16x8*>(
                    &xt[(rid * 34 + zid) * ZS + kb * 32 + chb]);
            }
#pragma unroll
            for (int mt = 0; mt < 2; ++mt)
#pragma unroll
                for (int nt = 0; nt < 2; ++nt)
                    acc[mt][nt] = __builtin_amdgcn_mfma_f32_16x16x32_bf16(
                        afr[mt], bfr[nt], acc[mt][nt], 0, 0, 0);
        }
    }

    // ---- epilogue: C/D layout col=lane&15, row=(lane>>4)*4+reg ----
    float* obase = out + (((b * 32 + X) * 32 + (y0 + mh)) * 32) * 64;
#pragma unroll
    for (int mt = 0; mt < 2; ++mt)
#pragma unroll
        for (int nt = 0; nt < 2; ++nt) {
            const int col = nh * 32 + nt * 16 + l15;
#pragma unroll
            for (int qq = 0; qq < 4; ++qq) {
                const int z = mt * 16 + kg * 4 + qq;
                obase[z * 64 + col] = acc[mt][nt][qq];
            }
        }
}

extern "C" void kernel_launch(void* const* d_in, const int* in_sizes, int n_in,
                              void* d_out, int out_size, void* d_ws, size_t ws_size,
                              hipStream_t stream)
{
    const float* x    = (const float*)d_in[0];
    const float* Wsc0 = (const float*)d_in[1];
    const float* Wsc1 = (const float*)d_in[2];
    const float* w1   = (const float*)d_in[3];
    const float* w2   = (const float*)d_in[4];
    const float* w3   = (const float*)d_in[5];
    const float* w4   = (const float*)d_in[6];
    float* out = (float*)d_out;

    build_k<<<dim3(27), dim3(64), 0, stream>>>(Wsc0, Wsc1, w1, w2, w3, w4);
    conv_mfma<<<dim3(2048), dim3(256), 0, stream>>>(x, out);
}

// Round 2
// 108.070 us; speedup vs baseline: 1.0295x; 1.0295x over previous
//
#include <hip/hip_runtime.h>

typedef unsigned short u16;
typedef unsigned int u32;
typedef __bf16 bf16x8 __attribute__((ext_vector_type(8)));
typedef float f32x4 __attribute__((ext_vector_type(4)));
typedef u32 u32x4 __attribute__((ext_vector_type(4)));

// kT[t][c][r]: bf16 bits of conv kernel, transposed so B-fragment k-reads are contiguous.
__device__ __align__(16) u16 g_kT[27 * 64 * 64];

__device__ __forceinline__ u16 f2bf(float f) {
    unsigned int u = __float_as_uint(f);
    u += 0x7FFFu + ((u >> 16) & 1u);   // RNE
    return (u16)(u >> 16);
}

// pack two fp32 -> one u32 holding two bf16 (round-half-up via +0x8000, then byte perm)
__device__ __forceinline__ u32 pack_bf(float a, float b) {
    u32 ua = __float_as_uint(a) + 0x8000u;
    u32 ub = __float_as_uint(b) + 0x8000u;
    // D bytes: [0,1]=a bytes[2,3] (S1), [2,3]=b bytes[6,7] (S0)  -> sel 0x07060302
    return __builtin_amdgcn_perm(ub, ua, 0x07060302u);
}

// ---------------------------------------------------------------------------
// Build kT[27][64][64] from w1..w4 (+ fold self-connection into center tap).
// ---------------------------------------------------------------------------
__global__ __launch_bounds__(64) void build_k(
    const float* __restrict__ Wsc0, const float* __restrict__ Wsc1,
    const float* __restrict__ w1, const float* __restrict__ w2,
    const float* __restrict__ w3, const float* __restrict__ w4)
{
    const int t = blockIdx.x;      // tap 0..26
    const int c = threadIdx.x;     // output column 0..63
    const int dx = t / 9 - 1, dy = (t / 3) % 3 - 1, dz = t % 3 - 1;
    const float d = sqrtf((float)(dx * dx + dy * dy + dz * dz));
    const float step = 1.5f / 9.0f;
    float emb[8];
#pragma unroll
    for (int k = 0; k < 8; ++k) {
        float diff = (d - (float)(k + 1) * step) / step;
        float q = diff * diff;
        emb[k] = (q < 1.0f) ? 1.14136f * expf(2.0f - 2.0f / (1.0f - q)) : 0.0f;
    }
    const float dn = fmaxf(d, 1e-12f);
    const float s3 = 1.7320508075688772f;
    const float sh1[3] = { s3 * (float)dx / dn, s3 * (float)dy / dn, s3 * (float)dz / dn };
    const float alpha  = 0.17677669529663687f;          // 1/sqrt(2*MUL)
    const float alpha3 = alpha * 0.57735026918962576f;  // alpha/sqrt(3)

    u16* outp = &g_kT[(t * 64 + c) * 64];
    if (c < 16) {
        const int o = c;
#pragma unroll
        for (int i = 0; i < 16; ++i) {
            float W1 = 0.f, W4 = 0.f;
#pragma unroll
            for (int k = 0; k < 8; ++k) {
                W1 += emb[k] * w1[k * 256 + i * 16 + o];
                W4 += emb[k] * w4[k * 256 + i * 16 + o];
            }
            W1 *= (1.0f / 27.0f); W4 *= (1.0f / 27.0f);
            float v0 = alpha * W1;
            if (t == 13) v0 += 0.25f * Wsc0[i * 16 + o];   // sc scalar block
            outp[i] = f2bf(v0);
            const float base = alpha3 * W4;
#pragma unroll
            for (int m = 0; m < 3; ++m) outp[16 + 3 * i + m] = f2bf(base * sh1[m]);
        }
    } else {
        const int o = (c - 16) / 3, nc = (c - 16) % 3;
#pragma unroll
        for (int i = 0; i < 16; ++i) {
            float W2 = 0.f, W3 = 0.f;
#pragma unroll
            for (int k = 0; k < 8; ++k) {
                W2 += emb[k] * w2[k * 256 + i * 16 + o];
                W3 += emb[k] * w3[k * 256 + i * 16 + o];
            }
            W2 *= (1.0f / 27.0f); W3 *= (1.0f / 27.0f);
            outp[i] = f2bf(alpha * W2 * sh1[nc]);
#pragma unroll
            for (int m = 0; m < 3; ++m) {
                float v = (m == nc) ? alpha * W3 : 0.0f;
                if (t == 13 && m == nc) v += 0.25f * Wsc1[i * 16 + o];  // sc vector block
                outp[16 + 3 * i + m] = f2bf(v);
            }
        }
    }
}

// ---------------------------------------------------------------------------
// Implicit-GEMM conv: block = (b, X, y0..y0+1) -> M=64 positions, N=64 ch.
// LDS tile: [dx(3)][yi(4)][zid(34)][ch..] bf16, z-row stride ZS=68 u16
// (34 dwords -> bank step 2 -> 2-way = conflict-free for b128 reads/writes).
// ---------------------------------------------------------------------------
#define ZS 68
#define NROWS 408   // 12 * 34

__global__ __launch_bounds__(256, 2) void conv_mfma(
    const float* __restrict__ x, float* __restrict__ out)
{
    __shared__ __align__(16) u16 xt[NROWS * ZS];

    // XCD-aware swizzle: 2048 % 8 == 0, bijective. Each XCD gets a contiguous
    // (b, X, y) panel -> y/X halo reuse and kT stay in one L2.
    const int bid0 = blockIdx.x;
    const int bid  = (bid0 & 7) * 256 + (bid0 >> 3);

    const int b   = bid >> 9;
    const int X   = (bid >> 4) & 31;
    const int y0  = (bid & 15) << 1;
    const int tid = threadIdx.x;

    // ---- stage: global fp32 -> LDS bf16 (12 rows x 34 z x 64 ch) ----
    {
        const int pr = tid >> 2;    // (rid,zid) row slot 0..63
        const int q  = tid & 3;     // channel quad (16 ch each)
#pragma unroll
        for (int pass = 0; pass < 7; ++pass) {
            const int idx = pass * 64 + pr;
            if (idx < NROWS) {
                const int rid = idx / 34;
                const int zid = idx - rid * 34;
                const int xin = X + (rid >> 2) - 1;
                const int yin = y0 + (rid & 3) - 1;
                const int zin = zid - 1;
                u32x4 p0 = {0u, 0u, 0u, 0u}, p1 = {0u, 0u, 0u, 0u};
                if ((unsigned)xin < 32u && (unsigned)yin < 32u && (unsigned)zin < 32u) {
                    const float4* src = reinterpret_cast<const float4*>(
                        x + ((((b * 32 + xin) * 32 + yin) * 32 + zin) * 64 + q * 16));
                    float4 v0 = src[0], v1 = src[1], v2 = src[2], v3 = src[3];
                    p0[0] = pack_bf(v0.x, v0.y); p0[1] = pack_bf(v0.z, v0.w);
                    p0[2] = pack_bf(v1.x, v1.y); p0[3] = pack_bf(v1.z, v1.w);
                    p1[0] = pack_bf(v2.x, v2.y); p1[1] = pack_bf(v2.z, v2.w);
                    p1[2] = pack_bf(v3.x, v3.y); p1[3] = pack_bf(v3.z, v3.w);
                }
                u16* dst = &xt[idx * ZS + q * 16];
                *reinterpret_cast<u32x4*>(dst)     = p0;
                *reinterpret_cast<u32x4*>(dst + 8) = p1;
            }
        }
    }
    __syncthreads();

    const int w    = tid >> 6;      // wave 0..3
    const int lane = tid & 63;
    const int l15  = lane & 15;
    const int kg   = lane >> 4;     // k-group 0..3
    const int mh   = w >> 1;        // M half (y' index)
    const int nh   = w & 1;         // N half
    const int chb  = kg * 8;

    // per-lane bases; all per-tap offsets fold to compile-time immediates
    const u16* abase = &xt[l15 * ZS + chb];
    const u16* bbase = &g_kT[(nh * 32 + l15) * 64 + chb];

    const f32x4 z4 = {0.f, 0.f, 0.f, 0.f};
    f32x4 acc[2][2] = {{z4, z4}, {z4, z4}};

    // 19 non-zero taps (center + 6 faces + 12 edges; corners are exactly 0)
    constexpr int NT = 19;
    constexpr int TAPS[NT] = {1,3,4,5,7,9,10,11,12,13,14,15,16,17,19,21,22,23,25};

    bf16x8 B[3][4];   // rolling B prefetch, distance 2 (L2 latency ~200-300 cy)
    bf16x8 A[2][4];   // rolling A prefetch, distance 1 (LDS latency)

    auto loadB = [&](int ti, bf16x8* Bs) {
        const int t = TAPS[ti];
#pragma unroll
        for (int kb = 0; kb < 2; ++kb)
#pragma unroll
        for (int nt = 0; nt < 2; ++nt)
            Bs[kb * 2 + nt] = *reinterpret_cast<const bf16x8*>(
                bbase + (t * 64 + nt * 16) * 64 + kb * 32);
    };
    auto loadA = [&](int ti, bf16x8* As) {
        const int t = TAPS[ti];
        const int dxt = t / 9, dyt = (t / 3) % 3, dzt = t % 3;
        const int rid = dxt * 4 + mh + dyt;
#pragma unroll
        for (int kb = 0; kb < 2; ++kb)
#pragma unroll
        for (int mt = 0; mt < 2; ++mt)
            As[kb * 2 + mt] = *reinterpret_cast<const bf16x8*>(
                abase + (rid * 34 + dzt + mt * 16) * ZS + kb * 32);
    };

    loadB(0, B[0]);
    loadB(1, B[1]);
    loadA(0, A[0]);

#pragma unroll
    for (int ti = 0; ti < NT; ++ti) {
        if (ti + 2 < NT) loadB(ti + 2, B[(ti + 2) % 3]);
        if (ti + 1 < NT) loadA(ti + 1, A[(ti + 1) & 1]);
        const bf16x8* Bc = B[ti % 3];
        const bf16x8* Ac = A[ti & 1];
        // swapped operands: D rows = out-channels -> contiguous 4-ch per lane
#pragma unroll
        for (int kb = 0; kb < 2; ++kb)
#pragma unroll
        for (int mt = 0; mt < 2; ++mt)
#pragma unroll
        for (int nt = 0; nt < 2; ++nt)
            acc[mt][nt] = __builtin_amdgcn_mfma_f32_16x16x32_bf16(
                Bc[kb * 2 + nt], Ac[kb * 2 + mt], acc[mt][nt], 0, 0, 0);
    }

    // ---- epilogue: lane holds ch = nh*32 + nt*16 + kg*4 + 0..3 at z = mt*16+l15 ----
    float* obase = out + (((b * 32 + X) * 32 + (y0 + mh)) * 32) * 64 + nh * 32 + kg * 4;
#pragma unroll
    for (int mt = 0; mt < 2; ++mt)
#pragma unroll
        for (int nt = 0; nt < 2; ++nt) {
            float4 v;
            v.x = acc[mt][nt][0]; v.y = acc[mt][nt][1];
            v.z = acc[mt][nt][2]; v.w = acc[mt][nt][3];
            *reinterpret_cast<float4*>(obase + (mt * 16 + l15) * 64 + nt * 16) = v;
        }
}

extern "C" void kernel_launch(void* const* d_in, const int* in_sizes, int n_in,
                              void* d_out, int out_size, void* d_ws, size_t ws_size,
                              hipStream_t stream)
{
    const float* x    = (const float*)d_in[0];
    const float* Wsc0 = (const float*)d_in[1];
    const float* Wsc1 = (const float*)d_in[2];
    const float* w1   = (const float*)d_in[3];
    const float* w2   = (const float*)d_in[4];
    const float* w3   = (const float*)d_in[5];
    const float* w4   = (const float*)d_in[6];
    float* out = (float*)d_out;

    build_k<<<dim3(27), dim3(64), 0, stream>>>(Wsc0, Wsc1, w1, w2, w3, w4);
    conv_mfma<<<dim3(2048), dim3(256), 0, stream>>>(x, out);
}